// Round 1
// baseline (6634.329 us; speedup 1.0000x reference)
//
#include <hip/hip_runtime.h>
#include <math.h>

#define D 128
#define MAXNORM (1.0f - 4e-3f)
#define ART_CLAMP 0.9999999f  /* fp32(1 - 1e-7) */

// ---------------- reduction helpers (block = 128 threads = 2 waves) ----------

__device__ __forceinline__ float waveReduce(float v) {
#pragma unroll
    for (int off = 32; off; off >>= 1) v += __shfl_down(v, off, 64);
    return v;
}

// Reduces K values across the 128-thread block; all threads receive totals.
// red must hold 2*K floats. Ends with __syncthreads().
template <int K>
__device__ __forceinline__ void blockReduceK(float* v, float* red, int tid) {
#pragma unroll
    for (int i = 0; i < K; i++) v[i] = waveReduce(v[i]);
    if ((tid & 63) == 0) {
        int w = tid >> 6;
#pragma unroll
        for (int i = 0; i < K; i++) red[w * K + i] = v[i];
    }
    __syncthreads();
#pragma unroll
    for (int i = 0; i < K; i++) v[i] = red[i] + red[K + i];
    __syncthreads();
}

// ---------------- hyperbolic bias: hb = proj(expmap0(b)) ---------------------

__global__ __launch_bounds__(128) void biasKernel(const float* __restrict__ B1,
                                                  const float* __restrict__ B2,
                                                  float* __restrict__ HBOUT) {
    __shared__ float red[2];
    int tid = threadIdx.x;
    const float* B = blockIdx.x ? B2 : B1;
    float v = B[tid];
    float s[1] = {v * v};
    blockReduceK<1>(s, red, tid);
    float nn = fmaxf(sqrtf(s[0]), 1e-15f);
    float t = tanhf(nn);
    float p = t * v / nn;
    float pn = fmaxf(t, 1e-15f);
    if (pn > MAXNORM) p *= MAXNORM / pn;
    HBOUT[blockIdx.x * D + tid] = p;
}

// ---------------- stage A: xt = logmap0(proj(mobius_add(proj(mv(W,p)), hb)))
// ENCODE: p = proj(expmap0(X_row)) first (layer-1 fuses the encoder).

template <bool ENCODE>
__global__ __launch_bounds__(128) void stageA(const float* __restrict__ X,
                                              const float* __restrict__ W,
                                              const float* __restrict__ HB,
                                              float* __restrict__ XT, int n) {
    __shared__ float wt[128 * 129];  // W transposed, padded: wt[k*129+j] = W[j][k]
    __shared__ float pt[4][128];
    __shared__ float hbs[128];
    __shared__ float red[16];
    int tid = threadIdx.x;

    for (int i = tid; i < 128 * 128; i += 128) {
        int j = i >> 7, k = i & 127;
        wt[k * 129 + j] = W[i];
    }
    hbs[tid] = HB[tid];
    __syncthreads();
    float hbv = hbs[tid];
    float t0[1] = {hbv * hbv};
    blockReduceK<1>(t0, red, tid);
    float hb2 = t0[0];

    for (int base = blockIdx.x * 4; base < n; base += gridDim.x * 4) {
        int mmax = min(4, n - base);
        float v[4], xns[4], sq[4];
#pragma unroll
        for (int m = 0; m < 4; m++) {
            v[m] = (m < mmax) ? X[(size_t)(base + m) * D + tid] : 0.0f;
            sq[m] = v[m] * v[m];
        }
        blockReduceK<4>(sq, red, tid);
#pragma unroll
        for (int m = 0; m < 4; m++) {
            if (ENCODE) {
                float nn = fmaxf(sqrtf(sq[m]), 1e-15f);
                float t = tanhf(nn);
                float p = t * v[m] / nn;   // expmap0
                float pn = fmaxf(t, 1e-15f);
                if (pn > MAXNORM) { p *= MAXNORM / pn; pn = MAXNORM; }
                v[m] = p;
                xns[m] = pn;
            } else {
                xns[m] = fmaxf(sqrtf(sq[m]), 1e-15f);
            }
            pt[m][tid] = v[m];
        }
        __syncthreads();

        // mx[j] = sum_k p[k] * W[j][k]
        float acc[4] = {0.f, 0.f, 0.f, 0.f};
#pragma unroll 4
        for (int k = 0; k < 128; k++) {
            float wv = wt[k * 129 + tid];
            acc[0] += pt[0][k] * wv;
            acc[1] += pt[1][k] * wv;
            acc[2] += pt[2][k] * wv;
            acc[3] += pt[3][k] * wv;
        }

        float mxn2[4];
#pragma unroll
        for (int m = 0; m < 4; m++) mxn2[m] = acc[m] * acc[m];
        blockReduceK<4>(mxn2, red, tid);

        float hv[4];
#pragma unroll
        for (int m = 0; m < 4; m++) {
            float mxn = fmaxf(sqrtf(mxn2[m]), 1e-15f);
            float arg = (mxn / xns[m]) * atanhf(fminf(xns[m], ART_CLAMP));
            float t = tanhf(arg);
            float s = (mxn2[m] == 0.0f) ? 0.0f : (t / mxn);  // zero-row guard
            float h = acc[m] * s;
            float rn = fmaxf(t, 1e-15f);   // ||res|| == t analytically
            if (rn > MAXNORM) h *= MAXNORM / rn;
            hv[m] = h;
        }

        float dots[8];
#pragma unroll
        for (int m = 0; m < 4; m++) { dots[m] = hv[m] * hv[m]; dots[4 + m] = hv[m] * hbv; }
        blockReduceK<8>(dots, red, tid);

        float av[4], an2[4];
#pragma unroll
        for (int m = 0; m < 4; m++) {
            float x2 = dots[m], xy = dots[4 + m];
            float k1 = 1.0f + 2.0f * xy + hb2;
            float num = k1 * hv[m] + (1.0f - x2) * hbv;
            float den = 1.0f + 2.0f * xy + x2 * hb2;
            av[m] = num / fmaxf(den, 1e-15f);
            an2[m] = av[m] * av[m];
        }
        blockReduceK<4>(an2, red, tid);
#pragma unroll
        for (int m = 0; m < 4; m++) {
            if (m < mmax) {
                float an = fmaxf(sqrtf(an2[m]), 1e-15f);
                float a = av[m];
                if (an > MAXNORM) { a *= MAXNORM / an; an = MAXNORM; }
                float lm = atanhf(fminf(an, ART_CLAMP)) / an;  // logmap0
                XT[(size_t)(base + m) * D + tid] = a * lm;
            }
        }
        // trailing __syncthreads from blockReduceK protects pt for next iter
    }
}

// ---------------- SpMM: agg[dst] += xt[src] * w  (edge-parallel atomics) -----

__global__ __launch_bounds__(256) void spmm(const float* __restrict__ XT,
                                            const int* __restrict__ DST,
                                            const int* __restrict__ SRC,
                                            const float* __restrict__ EW,
                                            float* __restrict__ AGG, int E) {
    long long gid = (long long)blockIdx.x * blockDim.x + threadIdx.x;
    long long e = gid >> 5;  // 32 lanes per edge, float4 each
    if (e >= E) return;
    int lane = (int)(gid & 31);
    int s = SRC[e], d = DST[e];
    float w = EW[e];
    const float4 v = ((const float4*)(XT + (size_t)s * D))[lane];
    float* out = AGG + (size_t)d * D + lane * 4;
    atomicAdd(out + 0, v.x * w);
    atomicAdd(out + 1, v.y * w);
    atomicAdd(out + 2, v.z * w);
    atomicAdd(out + 3, v.w * w);
}

// ---------------- stage C: out = proj(expmap0(relu(logmap0(proj(expmap0(agg))))))

__global__ __launch_bounds__(128) void stageC(const float* __restrict__ AGG,
                                              float* __restrict__ OUT, int n) {
    __shared__ float red[8];
    int tid = threadIdx.x;
    for (int base = blockIdx.x * 4; base < n; base += gridDim.x * 4) {
        int mmax = min(4, n - base);
        float v[4], n2[4];
#pragma unroll
        for (int m = 0; m < 4; m++) {
            v[m] = (m < mmax) ? AGG[(size_t)(base + m) * D + tid] : 0.0f;
            n2[m] = v[m] * v[m];
        }
        blockReduceK<4>(n2, red, tid);
        float r[4], r2[4];
#pragma unroll
        for (int m = 0; m < 4; m++) {
            float nn = fmaxf(sqrtf(n2[m]), 1e-15f);
            float t = tanhf(nn);
            float h = t * v[m] / nn;  // expmap0
            float pn = fmaxf(t, 1e-15f);
            if (pn > MAXNORM) { h *= MAXNORM / pn; pn = MAXNORM; }
            float lm = atanhf(fminf(pn, ART_CLAMP)) / pn;  // logmap0
            r[m] = fmaxf(lm * h, 0.0f);                    // relu in tangent space
            r2[m] = r[m] * r[m];
        }
        blockReduceK<4>(r2, red, tid);
#pragma unroll
        for (int m = 0; m < 4; m++) {
            if (m < mmax) {
                float nn = fmaxf(sqrtf(r2[m]), 1e-15f);
                float t = tanhf(nn);
                float o = t * r[m] / nn;  // expmap0 at c_out
                float pn = fmaxf(t, 1e-15f);
                if (pn > MAXNORM) o *= MAXNORM / pn;
                OUT[(size_t)(base + m) * D + tid] = o;
            }
        }
    }
}

// ---------------- launcher ---------------------------------------------------

extern "C" void kernel_launch(void* const* d_in, const int* in_sizes, int n_in,
                              void* d_out, int out_size, void* d_ws, size_t ws_size,
                              hipStream_t stream) {
    const float* x  = (const float*)d_in[0];
    const int*   ei = (const int*)d_in[1];
    const float* ew = (const float*)d_in[2];
    const float* w1 = (const float*)d_in[3];
    const float* b1 = (const float*)d_in[4];
    const float* w2 = (const float*)d_in[5];
    const float* b2 = (const float*)d_in[6];
    int n = in_sizes[0] / D;
    int E = in_sizes[2];

    float* bufA = (float*)d_ws;               // [n*D]
    float* bufB = bufA + (size_t)n * D;       // [n*D]
    float* hb   = bufB + (size_t)n * D;       // [2*D]

    const int* dst = ei;      // edge_index[0] = segment ids (destinations)
    const int* src = ei + E;  // edge_index[1] = gather sources

    biasKernel<<<2, 128, 0, stream>>>(b1, b2, hb);

    const int gA = 512;                        // 2 blocks/CU (66 KB LDS each)
    const int gC = (n + 3) / 4;
    long long tot = (long long)E * 32;
    const int gS = (int)((tot + 255) / 256);
    size_t bufBytes = (size_t)n * D * sizeof(float);

    // ---- layer 1 (fused encoder) ----
    stageA<true><<<gA, 128, 0, stream>>>(x, w1, hb, bufA, n);
    hipMemsetAsync(bufB, 0, bufBytes, stream);
    spmm<<<gS, 256, 0, stream>>>(bufA, dst, src, ew, bufB, E);
    stageC<<<gC, 128, 0, stream>>>(bufB, bufA, n);   // h1 -> bufA

    // ---- layer 2 ----
    stageA<false><<<gA, 128, 0, stream>>>(bufA, w2, hb + D, bufB, n);
    hipMemsetAsync(bufA, 0, bufBytes, stream);
    spmm<<<gS, 256, 0, stream>>>(bufB, dst, src, ew, bufA, E);
    stageC<<<gC, 128, 0, stream>>>(bufA, (float*)d_out, n);
}

// Round 2
// 1071.963 us; speedup vs baseline: 6.1890x; 6.1890x over previous
//
#include <hip/hip_runtime.h>
#include <math.h>
#include <stdint.h>

#define D 128
#define MAXNORM (1.0f - 4e-3f)
#define ART_CLAMP 0.9999999f  /* fp32(1 - 1e-7) */

// ---------------- reduction helpers ------------------------------------------

__device__ __forceinline__ float waveReduce(float v) {
#pragma unroll
    for (int off = 32; off; off >>= 1) v += __shfl_down(v, off, 64);
    return v;
}

// butterfly all-reduce: every lane ends with the 64-lane total
__device__ __forceinline__ float waveAllReduce(float v) {
#pragma unroll
    for (int off = 32; off; off >>= 1) v += __shfl_xor(v, off, 64);
    return v;
}

// Reduces K values across a 128-thread block; all threads receive totals.
template <int K>
__device__ __forceinline__ void blockReduceK(float* v, float* red, int tid) {
#pragma unroll
    for (int i = 0; i < K; i++) v[i] = waveReduce(v[i]);
    if ((tid & 63) == 0) {
        int w = tid >> 6;
#pragma unroll
        for (int i = 0; i < K; i++) red[w * K + i] = v[i];
    }
    __syncthreads();
#pragma unroll
    for (int i = 0; i < K; i++) v[i] = red[i] + red[K + i];
    __syncthreads();
}

// ---------------- hyperbolic bias: hb = proj(expmap0(b)) ---------------------

__global__ __launch_bounds__(128) void biasKernel(const float* __restrict__ B1,
                                                  const float* __restrict__ B2,
                                                  float* __restrict__ HBOUT) {
    __shared__ float red[2];
    int tid = threadIdx.x;
    const float* B = blockIdx.x ? B2 : B1;
    float v = B[tid];
    float s[1] = {v * v};
    blockReduceK<1>(s, red, tid);
    float nn = fmaxf(sqrtf(s[0]), 1e-15f);
    float t = tanhf(nn);
    float p = t * v / nn;
    float pn = fmaxf(t, 1e-15f);
    if (pn > MAXNORM) p *= MAXNORM / pn;
    HBOUT[blockIdx.x * D + tid] = p;
}

// ---------------- CSR build --------------------------------------------------

__global__ __launch_bounds__(256) void histo(const int* __restrict__ DST,
                                             int* __restrict__ cnt, int E) {
    int e = blockIdx.x * 256 + threadIdx.x;
    if (e < E) atomicAdd(&cnt[DST[e]], 1);
}

// per-block exclusive scan over chunks of 1024 ints
__global__ __launch_bounds__(256) void scanBlocks(const int* __restrict__ cnt,
                                                  int* __restrict__ excl,
                                                  int* __restrict__ bsum, int n) {
    __shared__ int sd[256];
    int tid = threadIdx.x;
    int base = blockIdx.x * 1024 + tid * 4;
    int v0 = (base + 0 < n) ? cnt[base + 0] : 0;
    int v1 = (base + 1 < n) ? cnt[base + 1] : 0;
    int v2 = (base + 2 < n) ? cnt[base + 2] : 0;
    int v3 = (base + 3 < n) ? cnt[base + 3] : 0;
    int s = v0 + v1 + v2 + v3;
    sd[tid] = s;
    __syncthreads();
    for (int off = 1; off < 256; off <<= 1) {
        int t = (tid >= off) ? sd[tid - off] : 0;
        __syncthreads();
        sd[tid] += t;
        __syncthreads();
    }
    int ex = sd[tid] - s;
    if (tid == 255) bsum[blockIdx.x] = sd[255];
    if (base + 0 < n) excl[base + 0] = ex;
    ex += v0;
    if (base + 1 < n) excl[base + 1] = ex;
    ex += v1;
    if (base + 2 < n) excl[base + 2] = ex;
    ex += v2;
    if (base + 3 < n) excl[base + 3] = ex;
}

// scan the (<=256) block sums in place; also set rp[n] = E
__global__ __launch_bounds__(256) void scanSums(int* __restrict__ bsum, int nb,
                                                int* __restrict__ rp_last, int E) {
    __shared__ int sd[256];
    int tid = threadIdx.x;
    int v = (tid < nb) ? bsum[tid] : 0;
    sd[tid] = v;
    __syncthreads();
    for (int off = 1; off < 256; off <<= 1) {
        int t = (tid >= off) ? sd[tid - off] : 0;
        __syncthreads();
        sd[tid] += t;
        __syncthreads();
    }
    if (tid < nb) bsum[tid] = sd[tid] - v;
    if (tid == 0) *rp_last = E;
}

__global__ __launch_bounds__(256) void addOffsets(int* __restrict__ rp,
                                                  const int* __restrict__ bsum,
                                                  int* __restrict__ work, int n) {
    int i = blockIdx.x * 256 + threadIdx.x;
    if (i < n) {
        int v = rp[i] + bsum[i >> 10];
        rp[i] = v;
        work[i] = v;
    }
}

__global__ __launch_bounds__(256) void scatterEdges(const int* __restrict__ DST,
                                                    const int* __restrict__ SRC,
                                                    const float* __restrict__ EW,
                                                    int* __restrict__ work,
                                                    int2* __restrict__ sorted, int E) {
    int e = blockIdx.x * 256 + threadIdx.x;
    if (e < E) {
        int d = DST[e];
        int pos = atomicAdd(&work[d], 1);
        sorted[pos] = make_int2(SRC[e], __float_as_int(EW[e]));
    }
}

// ---------------- CSR aggregation: agg[i] = sum_j w_j * xt[src_j] ------------
// 32 lanes per node, float4 per lane; no atomics, single write per node.

__global__ __launch_bounds__(256) void aggCsr(const float* __restrict__ XT,
                                              const int* __restrict__ rp,
                                              const int2* __restrict__ sorted,
                                              float* __restrict__ AGG, int n) {
    int g = (blockIdx.x * 256 + threadIdx.x) >> 5;
    int lane = threadIdx.x & 31;
    if (g >= n) return;
    int beg = rp[g], end = rp[g + 1];
    float4 acc = make_float4(0.f, 0.f, 0.f, 0.f);
    int j = beg;
    for (; j + 1 < end; j += 2) {
        int2 s0 = sorted[j];
        int2 s1 = sorted[j + 1];
        float4 v0 = ((const float4*)(XT + (size_t)s0.x * D))[lane];
        float4 v1 = ((const float4*)(XT + (size_t)s1.x * D))[lane];
        float w0 = __int_as_float(s0.y), w1 = __int_as_float(s1.y);
        acc.x += v0.x * w0; acc.y += v0.y * w0; acc.z += v0.z * w0; acc.w += v0.w * w0;
        acc.x += v1.x * w1; acc.y += v1.y * w1; acc.z += v1.z * w1; acc.w += v1.w * w1;
    }
    if (j < end) {
        int2 s0 = sorted[j];
        float4 v0 = ((const float4*)(XT + (size_t)s0.x * D))[lane];
        float w0 = __int_as_float(s0.y);
        acc.x += v0.x * w0; acc.y += v0.y * w0; acc.z += v0.z * w0; acc.w += v0.w * w0;
    }
    ((float4*)(AGG + (size_t)g * D))[lane] = acc;
}

// ---------------- stage A: xt = logmap0(proj(mobius_add(proj(mv(W,p)), hb)))
// Wave-autonomous: each 64-lane wave owns 4 rows (lane holds cols tid, tid+64).
// W swizzled in LDS for conflict-free ds_read_b128; reductions = shfl_xor only.

template <bool ENCODE>
__global__ __launch_bounds__(256, 2) void stageA(const float* __restrict__ X,
                                                 const float* __restrict__ W,
                                                 const float* __restrict__ HB,
                                                 float* __restrict__ XT, int n) {
    __shared__ __align__(16) float wt[128 * 128];   // wt[j*128 + ((k+4j)&127)] = W[j][k]
    __shared__ __align__(16) float pt[4][4][128];   // [wave][m][k]
    __shared__ float hbs[128];
    int tid = threadIdx.x;
    int lane = tid & 63;
    int wv = tid >> 6;

    for (int i = tid; i < 128 * 128; i += 256) {
        int j = i >> 7, k = i & 127;
        wt[(j << 7) | ((k + 4 * j) & 127)] = W[i];
    }
    if (tid < 128) hbs[tid] = HB[tid];
    __syncthreads();

    float hb0 = hbs[lane], hb1 = hbs[lane + 64];
    float hb2 = waveAllReduce(hb0 * hb0 + hb1 * hb1);

    float* ptw = &pt[wv][0][0];
    int ngrp = (n + 3) >> 2;
    int stride = gridDim.x * 4;

    for (int rg = blockIdx.x * 4 + wv; rg < ngrp; rg += stride) {
        int base = rg * 4;
        int mmax = min(4, n - base);
        float2 v[4];
        float xns[4];
#pragma unroll
        for (int m = 0; m < 4; m++) {
            float a = 0.f, b = 0.f;
            if (m < mmax) {
                const float* row = X + (size_t)(base + m) * D;
                a = row[lane];
                b = row[lane + 64];
            }
            float s = waveAllReduce(a * a + b * b);
            if (ENCODE) {
                float nn = fmaxf(sqrtf(s), 1e-15f);
                float t = tanhf(nn);
                float sc = t / nn;            // expmap0
                float pn = fmaxf(t, 1e-15f);
                if (pn > MAXNORM) { sc *= MAXNORM / pn; pn = MAXNORM; }
                a *= sc; b *= sc;
                xns[m] = pn;
            } else {
                xns[m] = fmaxf(sqrtf(s), 1e-15f);
            }
            v[m] = make_float2(a, b);
            ptw[m * 128 + lane] = a;
            ptw[m * 128 + lane + 64] = b;
        }
        // wave-private LDS RAW: DS ops from one wave are processed in order;
        // this asm is a compiler reorder fence + drains the writes.
        asm volatile("s_waitcnt lgkmcnt(0)" ::: "memory");

        // mx[j] = sum_k p[k]*W[j][k], thread owns j = lane and j = lane+64
        float2 acc[4] = {{0.f, 0.f}, {0.f, 0.f}, {0.f, 0.f}, {0.f, 0.f}};
#pragma unroll 8
        for (int k = 0; k < 128; k += 4) {
            int o = (k + 4 * lane) & 127;   // same offset for j=lane and j=lane+64
            float4 wa = *(const float4*)&wt[(lane << 7) + o];
            float4 wb = *(const float4*)&wt[((lane + 64) << 7) + o];
#pragma unroll
            for (int m = 0; m < 4; m++) {
                float4 pm = *(const float4*)&ptw[m * 128 + k];
                acc[m].x += pm.x * wa.x + pm.y * wa.y + pm.z * wa.z + pm.w * wa.w;
                acc[m].y += pm.x * wb.x + pm.y * wb.y + pm.z * wb.z + pm.w * wb.w;
            }
        }
        asm volatile("" ::: "memory");  // keep next-iter pt writes after these reads

#pragma unroll
        for (int m = 0; m < 4; m++) {
            float mxn2 = waveAllReduce(acc[m].x * acc[m].x + acc[m].y * acc[m].y);
            float mxn = fmaxf(sqrtf(mxn2), 1e-15f);
            float arg = (mxn / xns[m]) * atanhf(fminf(xns[m], ART_CLAMP));
            float t = tanhf(arg);
            float sc = (mxn2 == 0.0f) ? 0.0f : (t / mxn);   // zero-row guard
            float hx = acc[m].x * sc, hy = acc[m].y * sc;
            float rn = fmaxf(t, 1e-15f);                    // ||res|| == t analytically
            float hn = rn;
            if (rn > MAXNORM) {
                float f = MAXNORM / rn;
                hx *= f; hy *= f; hn = MAXNORM;
            }
            // mobius_add(h, hb): x2 analytic = hn^2, xy needs a reduction
            float x2 = hn * hn;
            float xy = waveAllReduce(hx * hb0 + hy * hb1);
            float k1 = 1.0f + 2.0f * xy + hb2;
            float k2 = 1.0f - x2;
            float den = fmaxf(1.0f + 2.0f * xy + x2 * hb2, 1e-15f);
            float ax = (k1 * hx + k2 * hb0) / den;
            float ay = (k1 * hy + k2 * hb1) / den;
            float an2 = waveAllReduce(ax * ax + ay * ay);
            float an = fmaxf(sqrtf(an2), 1e-15f);
            if (an > MAXNORM) {
                float f = MAXNORM / an;
                ax *= f; ay *= f; an = MAXNORM;
            }
            float lm = atanhf(fminf(an, ART_CLAMP)) / an;    // logmap0
            if (m < mmax) {
                float* o = XT + (size_t)(base + m) * D;
                o[lane] = ax * lm;
                o[lane + 64] = ay * lm;
            }
        }
    }
}

// ---------------- stage C: out = proj(expmap0(relu(logmap0(proj(expmap0(agg))))))

__global__ __launch_bounds__(128) void stageC(const float* __restrict__ AGG,
                                              float* __restrict__ OUT, int n) {
    __shared__ float red[8];
    int tid = threadIdx.x;
    for (int base = blockIdx.x * 4; base < n; base += gridDim.x * 4) {
        int mmax = min(4, n - base);
        float v[4], n2[4];
#pragma unroll
        for (int m = 0; m < 4; m++) {
            v[m] = (m < mmax) ? AGG[(size_t)(base + m) * D + tid] : 0.0f;
            n2[m] = v[m] * v[m];
        }
        blockReduceK<4>(n2, red, tid);
        float r[4], r2[4];
#pragma unroll
        for (int m = 0; m < 4; m++) {
            float nn = fmaxf(sqrtf(n2[m]), 1e-15f);
            float t = tanhf(nn);
            float h = t * v[m] / nn;  // expmap0
            float pn = fmaxf(t, 1e-15f);
            if (pn > MAXNORM) { h *= MAXNORM / pn; pn = MAXNORM; }
            float lm = atanhf(fminf(pn, ART_CLAMP)) / pn;  // logmap0
            r[m] = fmaxf(lm * h, 0.0f);                    // relu in tangent space
            r2[m] = r[m] * r[m];
        }
        blockReduceK<4>(r2, red, tid);
#pragma unroll
        for (int m = 0; m < 4; m++) {
            if (m < mmax) {
                float nn = fmaxf(sqrtf(r2[m]), 1e-15f);
                float t = tanhf(nn);
                float o = t * r[m] / nn;  // expmap0 at c_out
                float pn = fmaxf(t, 1e-15f);
                if (pn > MAXNORM) o *= MAXNORM / pn;
                OUT[(size_t)(base + m) * D + tid] = o;
            }
        }
    }
}

// ---------------- launcher ---------------------------------------------------

extern "C" void kernel_launch(void* const* d_in, const int* in_sizes, int n_in,
                              void* d_out, int out_size, void* d_ws, size_t ws_size,
                              hipStream_t stream) {
    const float* x  = (const float*)d_in[0];
    const int*   ei = (const int*)d_in[1];
    const float* ew = (const float*)d_in[2];
    const float* w1 = (const float*)d_in[3];
    const float* b1 = (const float*)d_in[4];
    const float* w2 = (const float*)d_in[5];
    const float* b2 = (const float*)d_in[6];
    int n = in_sizes[0] / D;
    int E = in_sizes[2];

    // workspace layout (~65 MB; round-1 verified ws >= 102 MB)
    float* buf0 = (float*)d_ws;                                   // n*D floats
    int*   rp   = (int*)(buf0 + (size_t)n * D);                   // n+1
    int*   work = rp + (n + 1);                                   // n
    int*   bsum = work + n;                                       // 256
    uintptr_t p = (uintptr_t)(bsum + 256);
    int2*  sorted = (int2*)((p + 15) & ~(uintptr_t)15);           // E pairs
    float* hb = (float*)(sorted + E);                             // 2*D
    float* T1 = (float*)d_out;  // tangent features layer 1 / also H1 / A2 / out

    const int* dst = ei;      // edge_index[0] = segment ids (destinations)
    const int* src = ei + E;  // edge_index[1] = gather sources

    const int gE = (E + 255) / 256;
    const int gN = (n + 255) / 256;
    const int nb = (n + 1023) / 1024;   // <= 256 for n <= 262144

    biasKernel<<<2, 128, 0, stream>>>(b1, b2, hb);

    // ---- CSR build (edge_index shared by both layers) ----
    hipMemsetAsync(work, 0, (size_t)n * sizeof(int), stream);
    histo<<<gE, 256, 0, stream>>>(dst, work, E);
    scanBlocks<<<nb, 256, 0, stream>>>(work, rp, bsum, n);
    scanSums<<<1, 256, 0, stream>>>(bsum, nb, rp + n, E);
    addOffsets<<<gN, 256, 0, stream>>>(rp, bsum, work, n);
    scatterEdges<<<gE, 256, 0, stream>>>(dst, src, ew, work, sorted, E);

    const int gA = 512;              // 2 blocks/CU (72.5 KB LDS each)
    const int gAgg = (n + 7) / 8;    // 8 nodes per 256-thread block
    const int gC = (n + 3) / 4;

    // ---- layer 1 (fused encoder) ----
    stageA<true><<<gA, 256, 0, stream>>>(x, w1, hb, T1, n);          // x -> T1 (d_out)
    aggCsr<<<gAgg, 256, 0, stream>>>(T1, rp, sorted, buf0, n);       // T1 -> A1 (buf0)
    stageC<<<gC, 128, 0, stream>>>(buf0, T1, n);                     // A1 -> H1 (d_out)

    // ---- layer 2 ----
    stageA<false><<<gA, 256, 0, stream>>>(T1, w2, hb + D, buf0, n);  // H1 -> T2 (buf0)
    aggCsr<<<gAgg, 256, 0, stream>>>(buf0, rp, sorted, T1, n);       // T2 -> A2 (d_out)
    stageC<<<gC, 128, 0, stream>>>(T1, (float*)d_out, n);            // in-place epilogue
}

// Round 3
// 917.444 us; speedup vs baseline: 7.2313x; 1.1684x over previous
//
#include <hip/hip_runtime.h>
#include <math.h>
#include <stdint.h>

#define D 128
#define MAXNORM (1.0f - 4e-3f)
#define ART_CLAMP 0.9999999f  /* fp32(1 - 1e-7) */

// butterfly all-reduce: every lane ends with the 64-lane total
__device__ __forceinline__ float waveAllReduce(float v) {
#pragma unroll
    for (int off = 32; off; off >>= 1) v += __shfl_xor(v, off, 64);
    return v;
}

// ---------------- hyperbolic bias: hb = proj(expmap0(b)), one wave -----------

__global__ __launch_bounds__(64) void biasKernel(const float* __restrict__ B1,
                                                 const float* __restrict__ B2,
                                                 float* __restrict__ HBOUT) {
    int lane = threadIdx.x;
    const float* B = blockIdx.x ? B2 : B1;
    float v0 = B[lane], v1 = B[lane + 64];
    float nn = fmaxf(sqrtf(waveAllReduce(v0 * v0 + v1 * v1)), 1e-15f);
    float t = tanhf(nn);
    float sc = t / nn;
    float pn = fmaxf(t, 1e-15f);
    if (pn > MAXNORM) sc *= MAXNORM / pn;
    HBOUT[blockIdx.x * D + lane] = v0 * sc;
    HBOUT[blockIdx.x * D + lane + 64] = v1 * sc;
}

// ---------------- W transpose: Wt[k][j] = W[j][k] ----------------------------

__global__ __launch_bounds__(256) void transposeW(const float* __restrict__ W1,
                                                  const float* __restrict__ W2,
                                                  float* __restrict__ Wt1,
                                                  float* __restrict__ Wt2) {
    int idx = blockIdx.x * 256 + threadIdx.x;  // 0..16383
    int k = idx >> 7, j = idx & 127;
    Wt1[idx] = W1[j * 128 + k];
    Wt2[idx] = W2[j * 128 + k];
}

// ---------------- CSR build --------------------------------------------------

__global__ __launch_bounds__(256) void histo(const int* __restrict__ DST,
                                             int* __restrict__ cnt, int E) {
    int e = blockIdx.x * 256 + threadIdx.x;
    if (e < E) atomicAdd(&cnt[DST[e]], 1);
}

__global__ __launch_bounds__(256) void scanBlocks(const int* __restrict__ cnt,
                                                  int* __restrict__ excl,
                                                  int* __restrict__ bsum, int n) {
    __shared__ int sd[256];
    int tid = threadIdx.x;
    int base = blockIdx.x * 1024 + tid * 4;
    int v0 = (base + 0 < n) ? cnt[base + 0] : 0;
    int v1 = (base + 1 < n) ? cnt[base + 1] : 0;
    int v2 = (base + 2 < n) ? cnt[base + 2] : 0;
    int v3 = (base + 3 < n) ? cnt[base + 3] : 0;
    int s = v0 + v1 + v2 + v3;
    sd[tid] = s;
    __syncthreads();
    for (int off = 1; off < 256; off <<= 1) {
        int t = (tid >= off) ? sd[tid - off] : 0;
        __syncthreads();
        sd[tid] += t;
        __syncthreads();
    }
    int ex = sd[tid] - s;
    if (tid == 255) bsum[blockIdx.x] = sd[255];
    if (base + 0 < n) excl[base + 0] = ex;
    ex += v0;
    if (base + 1 < n) excl[base + 1] = ex;
    ex += v1;
    if (base + 2 < n) excl[base + 2] = ex;
    ex += v2;
    if (base + 3 < n) excl[base + 3] = ex;
}

__global__ __launch_bounds__(256) void scanSums(int* __restrict__ bsum, int nb,
                                                int* __restrict__ rp_last, int E) {
    __shared__ int sd[256];
    int tid = threadIdx.x;
    int v = (tid < nb) ? bsum[tid] : 0;
    sd[tid] = v;
    __syncthreads();
    for (int off = 1; off < 256; off <<= 1) {
        int t = (tid >= off) ? sd[tid - off] : 0;
        __syncthreads();
        sd[tid] += t;
        __syncthreads();
    }
    if (tid < nb) bsum[tid] = sd[tid] - v;
    if (tid == 0) *rp_last = E;
}

__global__ __launch_bounds__(256) void addOffsets(int* __restrict__ rp,
                                                  const int* __restrict__ bsum,
                                                  int* __restrict__ work, int n) {
    int i = blockIdx.x * 256 + threadIdx.x;
    if (i < n) {
        int v = rp[i] + bsum[i >> 10];
        rp[i] = v;
        work[i] = v;
    }
}

__global__ __launch_bounds__(256) void scatterEdges(const int* __restrict__ DST,
                                                    const int* __restrict__ SRC,
                                                    const float* __restrict__ EW,
                                                    int* __restrict__ work,
                                                    int2* __restrict__ sorted, int E) {
    int e = blockIdx.x * 256 + threadIdx.x;
    if (e < E) {
        int d = DST[e];
        int pos = atomicAdd(&work[d], 1);
        sorted[pos] = make_int2(SRC[e], __float_as_int(EW[e]));
    }
}

// ---------------- GEMM: Y = X @ W^T  (Wt pre-transposed: Wt[k][j]) -----------
// 128x128 tile, 256 threads, 8x8 register tile (rows blocked, cols strided 16).
// K staged in two 64-halves: LDS 66.3 KB -> 2 blocks/CU.

__global__ __launch_bounds__(256) void gemm128(const float* __restrict__ A,
                                               const float* __restrict__ Wt,
                                               float* __restrict__ Y, int n) {
    __shared__ float As[128 * 65];   // As[r][k'] stride 65 (conflict-free)
    __shared__ float Ws[64 * 129];   // Ws[k'][j] stride 129 (conflict-free)
    int tid = threadIdx.x;
    int tx = tid & 15, ty = tid >> 4;
    int rowBase = blockIdx.x * 128;

    float acc[8][8] = {};
    for (int half = 0; half < 2; half++) {
        if (half) __syncthreads();
        // stage A half-tile: 128 rows x 64 floats = 2048 float4, 8/thread
#pragma unroll
        for (int c = 0; c < 8; c++) {
            int f = c * 256 + tid;
            int r = f >> 4, k4 = (f & 15) << 2;
            int gr = rowBase + r;
            if (gr >= n) gr = n - 1;  // clamp; stores guarded below
            float4 v = *(const float4*)(A + (size_t)gr * D + half * 64 + k4);
            *(float4*)(As + r * 65 + k4) = v;
        }
        // stage Wt half: 64 k x 128 j = 2048 float4, 8/thread
#pragma unroll
        for (int c = 0; c < 8; c++) {
            int f = c * 256 + tid;
            int k = f >> 5, j4 = (f & 31) << 2;
            float4 v = *(const float4*)(Wt + (size_t)(half * 64 + k) * D + j4);
            *(float4*)(Ws + k * 129 + j4) = v;
        }
        __syncthreads();
#pragma unroll 4
        for (int k = 0; k < 64; k++) {
            float a[8], w[8];
#pragma unroll
            for (int r = 0; r < 8; r++) a[r] = As[(ty * 8 + r) * 65 + k];
#pragma unroll
            for (int c = 0; c < 8; c++) w[c] = Ws[k * 129 + tx + 16 * c];
#pragma unroll
            for (int r = 0; r < 8; r++)
#pragma unroll
                for (int c = 0; c < 8; c++) acc[r][c] += a[r] * w[c];
        }
    }
#pragma unroll
    for (int r = 0; r < 8; r++) {
        int gr = rowBase + ty * 8 + r;
        if (gr < n) {
            float* yr = Y + (size_t)gr * D + tx;
#pragma unroll
            for (int c = 0; c < 8; c++) yr[16 * c] = acc[r][c];
        }
    }
}

// ---------------- epilogue A: xt = logmap0(proj(mobius_add(proj(f(Y)), hb)))
// Row scaling hoisted out of the GEMM: mx = sc*y, ||mx|| = sc*||y||.
// ENCODE: sc from raw X row (layer 1). Else: sc=1, xn read from stored norms.

template <bool ENCODE>
__global__ __launch_bounds__(256) void epilogueA(const float* __restrict__ Y,
                                                 const float* __restrict__ X,
                                                 const float* __restrict__ XN,
                                                 const float* __restrict__ HB,
                                                 float* __restrict__ XT, int n) {
    int lane = threadIdx.x & 63;
    int wv = (blockIdx.x * 256 + threadIdx.x) >> 6;
    int nw = (gridDim.x * 256) >> 6;
    float hb0 = HB[lane], hb1 = HB[lane + 64];
    float hb2 = waveAllReduce(hb0 * hb0 + hb1 * hb1);

    for (int r = wv; r < n; r += nw) {
        const float* yr = Y + (size_t)r * D;
        float y0 = yr[lane], y1 = yr[lane + 64];
        float yn2 = waveAllReduce(y0 * y0 + y1 * y1);
        float sc, xns;
        if (ENCODE) {
            const float* xr = X + (size_t)r * D;
            float x0 = xr[lane], x1 = xr[lane + 64];
            float nn = fmaxf(sqrtf(waveAllReduce(x0 * x0 + x1 * x1)), 1e-15f);
            float t = tanhf(nn);
            sc = t / nn;                       // expmap0 scale
            float pn = fmaxf(t, 1e-15f);
            if (pn > MAXNORM) { sc *= MAXNORM / pn; pn = MAXNORM; }  // proj
            xns = pn;
        } else {
            sc = 1.0f;
            xns = fmaxf(XN[r], 1e-15f);
        }
        float mxn2 = sc * sc * yn2;
        float mxn = fmaxf(sqrtf(mxn2), 1e-15f);
        float arg = (mxn / xns) * atanhf(fminf(xns, ART_CLAMP));
        float t = tanhf(arg);
        float s2 = (mxn2 == 0.0f) ? 0.0f : (t / mxn);  // zero-row guard
        float hx = sc * y0 * s2, hy = sc * y1 * s2;
        float rn = fmaxf(t, 1e-15f);                   // ||res|| == t analytically
        float hn = rn;
        if (rn > MAXNORM) { float f = MAXNORM / rn; hx *= f; hy *= f; hn = MAXNORM; }
        // mobius_add(h, hb): x2 analytic, xy reduced
        float x2 = hn * hn;
        float xy = waveAllReduce(hx * hb0 + hy * hb1);
        float k1 = 1.0f + 2.0f * xy + hb2;
        float k2 = 1.0f - x2;
        float den = fmaxf(1.0f + 2.0f * xy + x2 * hb2, 1e-15f);
        float ax = (k1 * hx + k2 * hb0) / den;
        float ay = (k1 * hy + k2 * hb1) / den;
        float an2 = waveAllReduce(ax * ax + ay * ay);
        float an = fmaxf(sqrtf(an2), 1e-15f);
        if (an > MAXNORM) { float f = MAXNORM / an; ax *= f; ay *= f; an = MAXNORM; }
        float lm = atanhf(fminf(an, ART_CLAMP)) / an;   // logmap0
        float* o = XT + (size_t)r * D;
        o[lane] = ax * lm;
        o[lane + 64] = ay * lm;
    }
}

// ---------------- CSR aggregation: wave per node, float2/lane, unroll 4 ------

__global__ __launch_bounds__(256) void aggCsr(const float* __restrict__ XT,
                                              const int* __restrict__ rp,
                                              const int2* __restrict__ sorted,
                                              float* __restrict__ AGG, int n) {
    int g = (blockIdx.x * 256 + threadIdx.x) >> 6;
    int lane = threadIdx.x & 63;
    if (g >= n) return;
    int beg = rp[g], end = rp[g + 1];
    float a0 = 0.f, a1 = 0.f;
    int j = beg;
    for (; j + 3 < end; j += 4) {
        int2 s0 = sorted[j], s1 = sorted[j + 1], s2 = sorted[j + 2], s3 = sorted[j + 3];
        float2 v0 = *(const float2*)(XT + (size_t)s0.x * D + lane * 2);
        float2 v1 = *(const float2*)(XT + (size_t)s1.x * D + lane * 2);
        float2 v2 = *(const float2*)(XT + (size_t)s2.x * D + lane * 2);
        float2 v3 = *(const float2*)(XT + (size_t)s3.x * D + lane * 2);
        float w0 = __int_as_float(s0.y), w1 = __int_as_float(s1.y);
        float w2 = __int_as_float(s2.y), w3 = __int_as_float(s3.y);
        a0 += v0.x * w0 + v1.x * w1 + v2.x * w2 + v3.x * w3;
        a1 += v0.y * w0 + v1.y * w1 + v2.y * w2 + v3.y * w3;
    }
    for (; j < end; j++) {
        int2 s0 = sorted[j];
        float2 v0 = *(const float2*)(XT + (size_t)s0.x * D + lane * 2);
        float w0 = __int_as_float(s0.y);
        a0 += v0.x * w0;
        a1 += v0.y * w0;
    }
    *(float2*)(AGG + (size_t)g * D + lane * 2) = make_float2(a0, a1);
}

// ---------------- stage C + analytic output-norm store -----------------------

__global__ __launch_bounds__(256) void stageC(const float* __restrict__ AGG,
                                              float* __restrict__ OUT,
                                              float* __restrict__ HN, int n) {
    int lane = threadIdx.x & 63;
    int wv = (blockIdx.x * 256 + threadIdx.x) >> 6;
    int nw = (gridDim.x * 256) >> 6;
    for (int r = wv; r < n; r += nw) {
        const float* ar = AGG + (size_t)r * D;
        float v0 = ar[lane], v1 = ar[lane + 64];
        float nn = fmaxf(sqrtf(waveAllReduce(v0 * v0 + v1 * v1)), 1e-15f);
        float t = tanhf(nn);
        float sc = t / nn;                       // expmap0
        float pn = fmaxf(t, 1e-15f);
        if (pn > MAXNORM) { sc *= MAXNORM / pn; pn = MAXNORM; }  // proj
        float lm = atanhf(fminf(pn, ART_CLAMP)) / pn;            // logmap0
        float r0 = fmaxf(lm * sc * v0, 0.f);     // relu in tangent space
        float r1 = fmaxf(lm * sc * v1, 0.f);
        float rn = fmaxf(sqrtf(waveAllReduce(r0 * r0 + r1 * r1)), 1e-15f);
        float t2 = tanhf(rn);
        float sc2 = t2 / rn;                     // expmap0 at c_out
        float on = fmaxf(t2, 1e-15f);
        if (on > MAXNORM) { sc2 *= MAXNORM / on; on = MAXNORM; }
        float* o = OUT + (size_t)r * D;
        o[lane] = r0 * sc2;
        o[lane + 64] = r1 * sc2;
        if (HN != nullptr && lane == 0) HN[r] = on;  // next layer's _norm(x)
    }
}

// ---------------- launcher ---------------------------------------------------

extern "C" void kernel_launch(void* const* d_in, const int* in_sizes, int n_in,
                              void* d_out, int out_size, void* d_ws, size_t ws_size,
                              hipStream_t stream) {
    const float* x  = (const float*)d_in[0];
    const int*   ei = (const int*)d_in[1];
    const float* ew = (const float*)d_in[2];
    const float* w1 = (const float*)d_in[3];
    const float* b1 = (const float*)d_in[4];
    const float* w2 = (const float*)d_in[5];
    const float* b2 = (const float*)d_in[6];
    int n = in_sizes[0] / D;
    int E = in_sizes[2];

    // workspace layout (~65.5 MB)
    float* buf0 = (float*)d_ws;                    // n*D floats
    int*   rp   = (int*)(buf0 + (size_t)n * D);    // n+1
    int*   work = rp + (n + 1);                    // n
    int*   bsum = work + n;                        // 256
    float* hn   = (float*)(bsum + 256);            // n
    float* wt1  = hn + n;                          // 128*128
    float* wt2  = wt1 + 128 * 128;                 // 128*128
    float* hb   = wt2 + 128 * 128;                 // 2*D
    uintptr_t p = (uintptr_t)(hb + 2 * D);
    int2* sorted = (int2*)((p + 15) & ~(uintptr_t)15);  // E pairs
    float* Yd = (float*)d_out;                     // n*D scratch + final out

    const int* dst = ei;      // edge_index[0] = segment ids (destinations)
    const int* src = ei + E;  // edge_index[1] = gather sources

    const int gE = (E + 255) / 256;
    const int gN = (n + 255) / 256;
    const int nb = (n + 1023) / 1024;
    const int gG = (n + 127) / 128;    // gemm tiles
    const int gW = 1024;               // streaming wave kernels (grid-stride)
    const int gAgg = (n + 3) / 4;      // wave per node

    biasKernel<<<2, 64, 0, stream>>>(b1, b2, hb);
    transposeW<<<64, 256, 0, stream>>>(w1, w2, wt1, wt2);

    // ---- CSR build (edge_index shared by both layers) ----
    hipMemsetAsync(work, 0, (size_t)n * sizeof(int), stream);
    histo<<<gE, 256, 0, stream>>>(dst, work, E);
    scanBlocks<<<nb, 256, 0, stream>>>(work, rp, bsum, n);
    scanSums<<<1, 256, 0, stream>>>(bsum, nb, rp + n, E);
    addOffsets<<<gN, 256, 0, stream>>>(rp, bsum, work, n);
    scatterEdges<<<gE, 256, 0, stream>>>(dst, src, ew, work, sorted, E);

    // ---- layer 1 (encoder folded into epilogue) ----
    gemm128<<<gG, 256, 0, stream>>>(x, wt1, Yd, n);                         // X@W1^T -> d_out
    epilogueA<true><<<gW, 256, 0, stream>>>(Yd, x, nullptr, hb, buf0, n);   // T1 -> buf0
    aggCsr<<<gAgg, 256, 0, stream>>>(buf0, rp, sorted, Yd, n);              // A1 -> d_out
    stageC<<<gW, 256, 0, stream>>>(Yd, buf0, hn, n);                        // H1 -> buf0, hn

    // ---- layer 2 ----
    gemm128<<<gG, 256, 0, stream>>>(buf0, wt2, Yd, n);                      // H1@W2^T -> d_out
    epilogueA<false><<<gW, 256, 0, stream>>>(Yd, nullptr, hn, hb + D, buf0, n); // T2 -> buf0
    aggCsr<<<gAgg, 256, 0, stream>>>(buf0, rp, sorted, Yd, n);              // A2 -> d_out
    stageC<<<gW, 256, 0, stream>>>(Yd, (float*)d_out, nullptr, n);          // in-place epilogue
}

// Round 4
// 678.364 us; speedup vs baseline: 9.7799x; 1.3524x over previous
//
#include <hip/hip_runtime.h>
#include <math.h>
#include <stdint.h>

#define D 128
#define MAXNORM (1.0f - 4e-3f)
#define ART_CLAMP 0.9999999f  /* fp32(1 - 1e-7) */

// butterfly all-reduce: every lane ends with the 64-lane total
__device__ __forceinline__ float waveAllReduce(float v) {
#pragma unroll
    for (int off = 32; off; off >>= 1) v += __shfl_xor(v, off, 64);
    return v;
}

// all-reduce across a 16-lane group (lanes differing in low 4 bits)
__device__ __forceinline__ float reduce16(float v) {
    v += __shfl_xor(v, 8, 64);
    v += __shfl_xor(v, 4, 64);
    v += __shfl_xor(v, 2, 64);
    v += __shfl_xor(v, 1, 64);
    return v;
}

// fp32 -> bf16 bits, round-to-nearest-even
__device__ __forceinline__ uint16_t f2bf(float f) {
    uint32_t u = __float_as_uint(f);
    uint32_t r = u + 0x7FFFu + ((u >> 16) & 1u);
    return (uint16_t)(r >> 16);
}

// ---------------- hyperbolic bias: hb = proj(expmap0(b)), one wave -----------

__global__ __launch_bounds__(64) void biasKernel(const float* __restrict__ B1,
                                                 const float* __restrict__ B2,
                                                 float* __restrict__ HBOUT) {
    int lane = threadIdx.x;
    const float* B = blockIdx.x ? B2 : B1;
    float v0 = B[lane], v1 = B[lane + 64];
    float nn = fmaxf(sqrtf(waveAllReduce(v0 * v0 + v1 * v1)), 1e-15f);
    float t = tanhf(nn);
    float sc = t / nn;
    float pn = fmaxf(t, 1e-15f);
    if (pn > MAXNORM) sc *= MAXNORM / pn;
    HBOUT[blockIdx.x * D + lane] = v0 * sc;
    HBOUT[blockIdx.x * D + lane + 64] = v1 * sc;
}

// ---------------- W transpose: Wt[k][j] = W[j][k] ----------------------------

__global__ __launch_bounds__(256) void transposeW(const float* __restrict__ W1,
                                                  const float* __restrict__ W2,
                                                  float* __restrict__ Wt1,
                                                  float* __restrict__ Wt2) {
    int idx = blockIdx.x * 256 + threadIdx.x;  // 0..16383
    int k = idx >> 7, j = idx & 127;
    Wt1[idx] = W1[j * 128 + k];
    Wt2[idx] = W2[j * 128 + k];
}

// ---------------- raw row norms of X (for layer-1 encoder fold) --------------

__global__ __launch_bounds__(256) void rowNorms(const float* __restrict__ X,
                                                float* __restrict__ XN, int n) {
    int lane = threadIdx.x & 63;
    int wv = (blockIdx.x * 256 + threadIdx.x) >> 6;
    int nw = (gridDim.x * 256) >> 6;
    for (int r = wv; r < n; r += nw) {
        float2 v = *(const float2*)(X + (size_t)r * D + lane * 2);
        float nn = sqrtf(waveAllReduce(v.x * v.x + v.y * v.y));
        if (lane == 0) XN[r] = nn;
    }
}

// ---------------- CSR build --------------------------------------------------

__global__ __launch_bounds__(256) void histo(const int* __restrict__ DST,
                                             int* __restrict__ cnt, int E) {
    int e = blockIdx.x * 256 + threadIdx.x;
    if (e < E) atomicAdd(&cnt[DST[e]], 1);
}

__global__ __launch_bounds__(256) void scanBlocks(const int* __restrict__ cnt,
                                                  int* __restrict__ excl,
                                                  int* __restrict__ bsum, int n) {
    __shared__ int sd[256];
    int tid = threadIdx.x;
    int base = blockIdx.x * 1024 + tid * 4;
    int v0 = (base + 0 < n) ? cnt[base + 0] : 0;
    int v1 = (base + 1 < n) ? cnt[base + 1] : 0;
    int v2 = (base + 2 < n) ? cnt[base + 2] : 0;
    int v3 = (base + 3 < n) ? cnt[base + 3] : 0;
    int s = v0 + v1 + v2 + v3;
    sd[tid] = s;
    __syncthreads();
    for (int off = 1; off < 256; off <<= 1) {
        int t = (tid >= off) ? sd[tid - off] : 0;
        __syncthreads();
        sd[tid] += t;
        __syncthreads();
    }
    int ex = sd[tid] - s;
    if (tid == 255) bsum[blockIdx.x] = sd[255];
    if (base + 0 < n) excl[base + 0] = ex;
    ex += v0;
    if (base + 1 < n) excl[base + 1] = ex;
    ex += v1;
    if (base + 2 < n) excl[base + 2] = ex;
    ex += v2;
    if (base + 3 < n) excl[base + 3] = ex;
}

__global__ __launch_bounds__(256) void scanSums(int* __restrict__ bsum, int nb,
                                                int* __restrict__ rp_last, int E) {
    __shared__ int sd[256];
    int tid = threadIdx.x;
    int v = (tid < nb) ? bsum[tid] : 0;
    sd[tid] = v;
    __syncthreads();
    for (int off = 1; off < 256; off <<= 1) {
        int t = (tid >= off) ? sd[tid - off] : 0;
        __syncthreads();
        sd[tid] += t;
        __syncthreads();
    }
    if (tid < nb) bsum[tid] = sd[tid] - v;
    if (tid == 0) *rp_last = E;
}

__global__ __launch_bounds__(256) void addOffsets(int* __restrict__ rp,
                                                  const int* __restrict__ bsum,
                                                  int* __restrict__ work, int n) {
    int i = blockIdx.x * 256 + threadIdx.x;
    if (i < n) {
        int v = rp[i] + bsum[i >> 10];
        rp[i] = v;
        work[i] = v;
    }
}

__global__ __launch_bounds__(256) void scatterEdges(const int* __restrict__ DST,
                                                    const int* __restrict__ SRC,
                                                    const float* __restrict__ EW,
                                                    int* __restrict__ work,
                                                    int2* __restrict__ sorted, int E) {
    int e = blockIdx.x * 256 + threadIdx.x;
    if (e < E) {
        int d = DST[e];
        int pos = atomicAdd(&work[d], 1);
        sorted[pos] = make_int2(SRC[e], __float_as_int(EW[e]));
    }
}

// ---------------- fused GEMM + HypLinear epilogue ----------------------------
// Y = A @ Wt (128x128 tile, 8x8 reg tile), then per-row:
//   mx = sc*y (ENCODE folds expmap0/proj scale; else sc=1, xns = stored norm)
//   xt = logmap0(proj(mobius_add(proj(tanh(||mx||/xn*atanh(xn))*mx/||mx||), hb)))
// Row r is owned by the 16 lanes sharing ty -> reductions are reduce16.
// Output written as bf16 (feeds the gather-dominated aggregation).

template <bool ENCODE>
__global__ __launch_bounds__(256) void gemmA(const float* __restrict__ A,
                                             const float* __restrict__ Wt,
                                             const float* __restrict__ XN,
                                             const float* __restrict__ HB,
                                             uint16_t* __restrict__ XT, int n) {
    __shared__ float As[128 * 65];   // As[r][k'] stride 65
    __shared__ float Ws[64 * 129];   // Ws[k'][j] stride 129
    int tid = threadIdx.x;
    int tx = tid & 15, ty = tid >> 4;
    int rowBase = blockIdx.x * 128;

    float hbf[8];
#pragma unroll
    for (int c = 0; c < 8; c++) hbf[c] = HB[tx + 16 * c];
    float hbsq = 0.f;
#pragma unroll
    for (int c = 0; c < 8; c++) hbsq += hbf[c] * hbf[c];
    float hb2 = reduce16(hbsq);

    float acc[8][8] = {};
    for (int half = 0; half < 2; half++) {
        if (half) __syncthreads();
#pragma unroll
        for (int c = 0; c < 8; c++) {
            int f = c * 256 + tid;
            int r = f >> 4, k4 = (f & 15) << 2;
            int gr = rowBase + r;
            if (gr >= n) gr = n - 1;  // clamp; epilogue guarded
            float4 v = *(const float4*)(A + (size_t)gr * D + half * 64 + k4);
            *(float4*)(As + r * 65 + k4) = v;
        }
#pragma unroll
        for (int c = 0; c < 8; c++) {
            int f = c * 256 + tid;
            int k = f >> 5, j4 = (f & 31) << 2;
            float4 v = *(const float4*)(Wt + (size_t)(half * 64 + k) * D + j4);
            *(float4*)(Ws + k * 129 + j4) = v;
        }
        __syncthreads();
#pragma unroll 4
        for (int k = 0; k < 64; k++) {
            float a[8], w[8];
#pragma unroll
            for (int r = 0; r < 8; r++) a[r] = As[(ty * 8 + r) * 65 + k];
#pragma unroll
            for (int c = 0; c < 8; c++) w[c] = Ws[k * 129 + tx + 16 * c];
#pragma unroll
            for (int r = 0; r < 8; r++)
#pragma unroll
                for (int c = 0; c < 8; c++) acc[r][c] += a[r] * w[c];
        }
    }

    // ---- fused epilogue ----
#pragma unroll
    for (int r = 0; r < 8; r++) {
        int row = rowBase + ty * 8 + r;
        if (row >= n) continue;   // uniform across the 16-lane group
        float s = 0.f;
#pragma unroll
        for (int c = 0; c < 8; c++) s += acc[r][c] * acc[r][c];
        float yn2 = reduce16(s);
        float sc, xns;
        if (ENCODE) {
            float nn = fmaxf(XN[row], 1e-15f);
            float t = tanhf(nn);
            sc = t / nn;                        // expmap0 scale
            float pn = fmaxf(t, 1e-15f);
            if (pn > MAXNORM) { sc *= MAXNORM / pn; pn = MAXNORM; }  // proj
            xns = pn;
        } else {
            sc = 1.0f;
            xns = fmaxf(XN[row], 1e-15f);
        }
        float mxn2 = sc * sc * yn2;
        float mxn = fmaxf(sqrtf(mxn2), 1e-15f);
        float arg = (mxn / xns) * atanhf(fminf(xns, ART_CLAMP));
        float t = tanhf(arg);
        float s2 = (mxn2 == 0.0f) ? 0.0f : (sc * t / mxn);  // zero-row guard
        float h[8];
#pragma unroll
        for (int c = 0; c < 8; c++) h[c] = acc[r][c] * s2;
        float rn = fmaxf(t, 1e-15f);   // ||res|| == t analytically
        float hn = rn;
        if (rn > MAXNORM) {
            float f = MAXNORM / rn;
#pragma unroll
            for (int c = 0; c < 8; c++) h[c] *= f;
            hn = MAXNORM;
        }
        float x2 = hn * hn;
        float d0 = 0.f;
#pragma unroll
        for (int c = 0; c < 8; c++) d0 += h[c] * hbf[c];
        float xy = reduce16(d0);
        float k1 = 1.0f + 2.0f * xy + hb2;
        float k2 = 1.0f - x2;
        float den = fmaxf(1.0f + 2.0f * xy + x2 * hb2, 1e-15f);
        float av[8];
        float s3 = 0.f;
#pragma unroll
        for (int c = 0; c < 8; c++) {
            av[c] = (k1 * h[c] + k2 * hbf[c]) / den;
            s3 += av[c] * av[c];
        }
        float an = fmaxf(sqrtf(reduce16(s3)), 1e-15f);
        float fproj = 1.0f;
        if (an > MAXNORM) { fproj = MAXNORM / an; an = MAXNORM; }
        float lm = fproj * atanhf(fminf(an, ART_CLAMP)) / an;  // proj+logmap0
        uint16_t* o = XT + (size_t)row * D + tx;
#pragma unroll
        for (int c = 0; c < 8; c++) o[16 * c] = f2bf(av[c] * lm);
    }
}

// ---------------- fused CSR aggregation + HypAct (stage C) -------------------
// Wave per node: gather bf16 xt rows (4 B/lane), fp32 accumulate, then
// out = proj(expmap0(relu(logmap0(proj(expmap0(agg)))))) inline.
// STORE_HN: store analytic output norm for next layer's mobius_matvec.

template <bool STORE_HN>
__global__ __launch_bounds__(256) void aggC(const uint16_t* __restrict__ XT,
                                            const int* __restrict__ rp,
                                            const int2* __restrict__ sorted,
                                            float* __restrict__ OUT,
                                            float* __restrict__ HN, int n) {
    int g = (blockIdx.x * 256 + threadIdx.x) >> 6;
    int lane = threadIdx.x & 63;
    if (g >= n) return;
    int beg = rp[g], end = rp[g + 1];
    float a0 = 0.f, a1 = 0.f;
    int j = beg;
    for (; j + 3 < end; j += 4) {
        int2 s0 = sorted[j], s1 = sorted[j + 1], s2 = sorted[j + 2], s3 = sorted[j + 3];
        uint32_t u0 = ((const uint32_t*)(XT + (size_t)s0.x * D))[lane];
        uint32_t u1 = ((const uint32_t*)(XT + (size_t)s1.x * D))[lane];
        uint32_t u2 = ((const uint32_t*)(XT + (size_t)s2.x * D))[lane];
        uint32_t u3 = ((const uint32_t*)(XT + (size_t)s3.x * D))[lane];
        float w0 = __int_as_float(s0.y), w1 = __int_as_float(s1.y);
        float w2 = __int_as_float(s2.y), w3 = __int_as_float(s3.y);
        a0 += __uint_as_float(u0 << 16) * w0 + __uint_as_float(u1 << 16) * w1 +
              __uint_as_float(u2 << 16) * w2 + __uint_as_float(u3 << 16) * w3;
        a1 += __uint_as_float(u0 & 0xFFFF0000u) * w0 + __uint_as_float(u1 & 0xFFFF0000u) * w1 +
              __uint_as_float(u2 & 0xFFFF0000u) * w2 + __uint_as_float(u3 & 0xFFFF0000u) * w3;
    }
    for (; j < end; j++) {
        int2 s0 = sorted[j];
        uint32_t u0 = ((const uint32_t*)(XT + (size_t)s0.x * D))[lane];
        float w0 = __int_as_float(s0.y);
        a0 += __uint_as_float(u0 << 16) * w0;
        a1 += __uint_as_float(u0 & 0xFFFF0000u) * w0;
    }
    // ---- stage C inline ----
    float nn = fmaxf(sqrtf(waveAllReduce(a0 * a0 + a1 * a1)), 1e-15f);
    float t = tanhf(nn);
    float sc = t / nn;                       // expmap0
    float pn = fmaxf(t, 1e-15f);
    if (pn > MAXNORM) { sc *= MAXNORM / pn; pn = MAXNORM; }  // proj
    float lm = atanhf(fminf(pn, ART_CLAMP)) / pn;            // logmap0
    float r0 = fmaxf(lm * sc * a0, 0.f);     // relu in tangent space
    float r1 = fmaxf(lm * sc * a1, 0.f);
    float rn = fmaxf(sqrtf(waveAllReduce(r0 * r0 + r1 * r1)), 1e-15f);
    float t2 = tanhf(rn);
    float sc2 = t2 / rn;                     // expmap0 at c_out
    float on = fmaxf(t2, 1e-15f);
    if (on > MAXNORM) { sc2 *= MAXNORM / on; on = MAXNORM; }
    *(float2*)(OUT + (size_t)g * D + lane * 2) = make_float2(r0 * sc2, r1 * sc2);
    if (STORE_HN && lane == 0) HN[g] = on;   // next layer's _norm(x)
}

// ---------------- launcher ---------------------------------------------------

extern "C" void kernel_launch(void* const* d_in, const int* in_sizes, int n_in,
                              void* d_out, int out_size, void* d_ws, size_t ws_size,
                              hipStream_t stream) {
    const float* x  = (const float*)d_in[0];
    const int*   ei = (const int*)d_in[1];
    const float* ew = (const float*)d_in[2];
    const float* w1 = (const float*)d_in[3];
    const float* b1 = (const float*)d_in[4];
    const float* w2 = (const float*)d_in[5];
    const float* b2 = (const float*)d_in[6];
    int n = in_sizes[0] / D;
    int E = in_sizes[2];

    // workspace layout (~40 MB)
    uint16_t* xtb = (uint16_t*)d_ws;               // n*D bf16
    int*   rp   = (int*)(xtb + (size_t)n * D);     // n+1
    int*   work = rp + (n + 1);                    // n
    int*   bsum = work + n;                        // 256
    float* xn   = (float*)(bsum + 256);            // n (X norms, then H norms)
    float* wt1  = xn + n;                          // 128*128
    float* wt2  = wt1 + 128 * 128;                 // 128*128
    float* hb   = wt2 + 128 * 128;                 // 2*D
    uintptr_t p = (uintptr_t)(hb + 2 * D);
    int2* sorted = (int2*)((p + 15) & ~(uintptr_t)15);  // E pairs
    float* Hd = (float*)d_out;                     // H1 scratch + final out

    const int* dst = ei;      // edge_index[0] = segment ids (destinations)
    const int* src = ei + E;  // edge_index[1] = gather sources

    const int gE = (E + 255) / 256;
    const int gN = (n + 255) / 256;
    const int nb = (n + 1023) / 1024;
    const int gG = (n + 127) / 128;    // gemm tiles
    const int gAgg = (n + 3) / 4;      // wave per node

    biasKernel<<<2, 64, 0, stream>>>(b1, b2, hb);
    transposeW<<<64, 256, 0, stream>>>(w1, w2, wt1, wt2);
    rowNorms<<<1024, 256, 0, stream>>>(x, xn, n);

    // ---- CSR build (edge_index shared by both layers) ----
    hipMemsetAsync(work, 0, (size_t)n * sizeof(int), stream);
    histo<<<gE, 256, 0, stream>>>(dst, work, E);
    scanBlocks<<<nb, 256, 0, stream>>>(work, rp, bsum, n);
    scanSums<<<1, 256, 0, stream>>>(bsum, nb, rp + n, E);
    addOffsets<<<gN, 256, 0, stream>>>(rp, bsum, work, n);
    scatterEdges<<<gE, 256, 0, stream>>>(dst, src, ew, work, sorted, E);

    // ---- layer 1 (encoder folded into gemmA epilogue) ----
    gemmA<true><<<gG, 256, 0, stream>>>(x, wt1, xn, hb, xtb, n);        // -> bf16 T1
    aggC<true><<<gAgg, 256, 0, stream>>>(xtb, rp, sorted, Hd, xn, n);   // -> H1 (d_out) + hn

    // ---- layer 2 ----
    gemmA<false><<<gG, 256, 0, stream>>>(Hd, wt2, xn, hb + D, xtb, n);  // -> bf16 T2
    aggC<false><<<gAgg, 256, 0, stream>>>(xtb, rp, sorted, (float*)d_out, nullptr, n);
}